// Round 8
// baseline (143.561 us; speedup 1.0000x reference)
//
#include <hip/hip_runtime.h>

__device__ __forceinline__ float fexp2(float x) { return __builtin_amdgcn_exp2f(x); }
__device__ __forceinline__ float flog2(float x) { return __builtin_amdgcn_logf(x); }
__device__ __forceinline__ float ffma (float a, float b, float c) { return __builtin_fmaf(a, b, c); }
__device__ __forceinline__ float fmed3(float a, float lo, float hi) { return __builtin_amdgcn_fmed3f(a, lo, hi); }

#define LAB_EPS 0.008856f
#define F16_116 0.13793103448275862f   // 16/116
#define TSCALE  11.3137085f            // sqrt(128): u = (TSCALE*t)^2 has step 1/128 in t^2
#define TCLAMP  45.2547f               // TSCALE*4 (idx <= 2047)

// P=2 points/thread (R6's 62%-occupancy structure) x R4's table-tanh
// (zero transcendentals in hidden loop). Issue-port model: tanh via table
// = ~11 VALU (22cy) vs exp/rcp = 2 trans+2 VALU (36cy) per hidden unit;
// gather latency/conflicts live on the LDS pipe and hide under 16 waves/SIMD.
// Folded algebra: out = x@A + h@W2p + {fX,fY,fZ}@U + cv
__global__ __launch_bounds__(256) void fused_kernel(
    const float* __restrict__ x,
    const float* __restrict__ w_seq1, const float* __restrict__ b_seq1,
    const float* __restrict__ w_seq2, const float* __restrict__ b_seq2,
    const float* __restrict__ w_lin,  const float* __restrict__ b_lin,
    const float* __restrict__ w_comb, const float* __restrict__ b_comb,
    const float* __restrict__ w_logd, const float* __restrict__ b_logd,
    const float* __restrict__ w_final,const float* __restrict__ b_final,
    float* __restrict__ out, int n)
{
    __shared__ float  gtab[2048];  // g(u) = tanh(su)/(su*TSCALE), mid-point sampled
    __shared__ float4 wlds[128];   // 2j: TSCALE*{w1_0j,w1_1j,w1_2j,b1_j}, 2j+1: {w2p_j0..2,0}
    __shared__ float  smlds[33];   // A[9], U[9], Wld[9], bld[3], cv[3]

    const int tid = threadIdx.x;

    // ---- build tanh table (8 iters/thread) ----
    for (int k = tid; k < 2048; k += 256) {
        const float su = sqrtf((k + 0.5f) * (1.0f / 128.0f));
        gtab[k] = tanhf(su) / (su * TSCALE);
    }

    if (tid < 64) {
        const int j = tid;
        float H3[9];
        for (int i = 0; i < 3; ++i)
            for (int c = 0; c < 3; ++c) {
                float h = 0.f;
                for (int m = 0; m < 3; ++m) h += w_comb[(i + 3) * 3 + m] * w_final[m * 3 + c];
                H3[i * 3 + c] = h;
            }
        const float w0 = w_seq2[j * 3 + 0], w1 = w_seq2[j * 3 + 1], w2 = w_seq2[j * 3 + 2];
        wlds[2 * j]     = make_float4(w_seq1[j] * TSCALE, w_seq1[64 + j] * TSCALE,
                                      w_seq1[128 + j] * TSCALE, b_seq1[j] * TSCALE);
        wlds[2 * j + 1] = make_float4(w0 * H3[0] + w1 * H3[3] + w2 * H3[6],
                                      w0 * H3[1] + w1 * H3[4] + w2 * H3[7],
                                      w0 * H3[2] + w1 * H3[5] + w2 * H3[8], 0.f);
        if (j == 0) {
            float G[9], Wfb[9];
            for (int i = 0; i < 3; ++i)
                for (int c = 0; c < 3; ++c) {
                    float gg = 0.f;
                    for (int m = 0; m < 3; ++m) gg += w_comb[i * 3 + m] * w_final[m * 3 + c];
                    G[i * 3 + c] = gg;
                }
            for (int k = 0; k < 3; ++k)
                for (int c = 0; c < 3; ++c) {
                    float s = 0.f;
                    for (int i = 0; i < 3; ++i) s += w_lin[k * 3 + i] * G[i * 3 + c];
                    smlds[k * 3 + c] = s;                         // A
                    Wfb[k * 3 + c]   = w_final[(k + 3) * 3 + c];
                    smlds[18 + k * 3 + c] = w_logd[k * 3 + c];    // Wld
                }
            for (int c = 0; c < 3; ++c) {
                smlds[9 + c]     = 500.0f * Wfb[3 + c];                                         // fX row
                smlds[9 + 3 + c] = 116.0f * Wfb[c] - 500.0f * Wfb[3 + c] + 200.0f * Wfb[6 + c]; // fY row
                smlds[9 + 6 + c] = -200.0f * Wfb[6 + c];                                        // fZ row
                float s = b_final[c] - 16.0f * Wfb[c];
                for (int i = 0; i < 3; ++i)
                    s += b_lin[i] * G[i * 3 + c] + b_seq2[i] * H3[i * 3 + c]
                       + b_comb[i] * w_final[i * 3 + c];
                smlds[27 + c] = b_logd[c];
                smlds[30 + c] = s;                                // cv
            }
        }
    }
    __syncthreads();

    const int g = blockIdx.x * blockDim.x + tid;
    if (g * 2 >= n) return;

    // 2 points = 6 floats = 3 float2 (coalesced 8B loads)
    const float2* xin = reinterpret_cast<const float2*>(x) + (size_t)g * 3;
    const float2 v0 = xin[0], v1 = xin[1], v2 = xin[2];
    const float xs[2][3] = {{v0.x, v0.y, v1.x}, {v1.y, v2.x, v2.y}};

    float acc[2][3] = {{0.f, 0.f, 0.f}, {0.f, 0.f, 0.f}};

    // Hidden layer, table-tanh: t' = TSCALE*(x.w1+b1); clamp; h = t'*g[trunc(t'^2)]
#pragma unroll 8
    for (int j = 0; j < 64; ++j) {
        const float4 wa = wlds[2 * j];
        const float4 wb = wlds[2 * j + 1];
#pragma unroll
        for (int p = 0; p < 2; ++p) {
            float t = ffma(xs[p][0], wa.x, ffma(xs[p][1], wa.y, ffma(xs[p][2], wa.z, wa.w)));
            t = fmed3(t, -TCLAMP, TCLAMP);
            const float u = t * t;                  // <= 2047.99
            const int idx = (int)u;                 // v_cvt (trunc)
            const float h = t * gtab[idx];
            acc[p][0] = ffma(h, wb.x, acc[p][0]);
            acc[p][1] = ffma(h, wb.y, acc[p][1]);
            acc[p][2] = ffma(h, wb.z, acc[p][2]);
        }
    }

    // Epilogue constants
    float A[9], U[9], Wld[9], bld[3], cv[3];
#pragma unroll
    for (int i = 0; i < 9; ++i) { A[i] = smlds[i]; U[i] = smlds[9 + i]; Wld[i] = smlds[18 + i]; }
#pragma unroll
    for (int i = 0; i < 3; ++i) { bld[i] = smlds[27 + i]; cv[i] = smlds[30 + i]; }

    float ov[6];
#pragma unroll
    for (int p = 0; p < 2; ++p) {
        const float L = xs[p][0], aa = xs[p][1], bb = xs[p][2];
        // ---- lab2rgb(x) ----
        const float fy = (L + 16.0f) * (1.0f / 116.0f);
        const float fx = ffma(aa,  0.002f, fy);
        const float fz = ffma(bb, -0.005f, fy);
        float rgb[3];
        {
            const float f3x = fx * fx * fx, f3y = fy * fy * fy, f3z = fz * fz * fz;
            const float tx = f3x > LAB_EPS ? f3x : (fx - F16_116) * (1.0f / 7.787f);
            const float ty = f3y > LAB_EPS ? f3y : (fy - F16_116) * (1.0f / 7.787f);
            const float tz = f3z > LAB_EPS ? f3z : (fz - F16_116) * (1.0f / 7.787f);
            const float X = tx * 0.95047f, Y = ty, Z = tz * 1.08883f;
            const float linv[3] = {
                 3.2404542f * X - 1.5371385f * Y - 0.4985314f * Z,
                -0.9692660f * X + 1.8760108f * Y + 0.0415560f * Z,
                 0.0556434f * X - 0.2040259f * Y + 1.0572252f * Z};
#pragma unroll
            for (int c = 0; c < 3; ++c) {
                const float cc = linv[c];
                const float lo = 12.92f * cc;
                const float hi = ffma(1.055f,
                                      fexp2(flog2(fmaxf(cc, 0.0031308f)) * (1.0f / 2.4f)),
                                      -0.055f);
                rgb[c] = cc <= 0.0031308f ? lo : hi;
            }
        }
        // ---- -log10 -> @Wld+bld -> 10^ -> srgb_to_linear ----
        const float ld0 = -0.30102999566398120f * flog2(rgb[0]);
        const float ld1 = -0.30102999566398120f * flog2(rgb[1]);
        const float ld2 = -0.30102999566398120f * flog2(rgb[2]);
        float lin2[3];
#pragma unroll
        for (int c = 0; c < 3; ++c) {
            const float mp  = ffma(ld0, Wld[c], ffma(ld1, Wld[3 + c], ffma(ld2, Wld[6 + c], bld[c])));
            const float r10 = fexp2(mp * 3.3219280948873623f);   // 10^mp
            const float lo  = r10 * (1.0f / 12.92f);
            const float base = (fmaxf(r10, 0.04045f) + 0.055f) * (1.0f / 1.055f);
            const float hi  = fexp2(2.4f * flog2(base));
            lin2[c] = r10 <= 0.04045f ? lo : hi;
        }
        // ---- rgb2lab -> f-values ----
        const float X2 = (0.412453f * lin2[0] + 0.357580f * lin2[1] + 0.180423f * lin2[2]) * (1.0f / 0.95047f);
        const float Y2 =  0.212671f * lin2[0] + 0.715160f * lin2[1] + 0.072169f * lin2[2];
        const float Z2 = (0.019334f * lin2[0] + 0.119193f * lin2[1] + 0.950227f * lin2[2]) * (1.0f / 1.08883f);
        const float fX = X2 > LAB_EPS ? fexp2(flog2(fmaxf(X2, LAB_EPS)) * (1.0f / 3.0f)) : ffma(7.787f, X2, F16_116);
        const float fY = Y2 > LAB_EPS ? fexp2(flog2(fmaxf(Y2, LAB_EPS)) * (1.0f / 3.0f)) : ffma(7.787f, Y2, F16_116);
        const float fZ = Z2 > LAB_EPS ? fexp2(flog2(fmaxf(Z2, LAB_EPS)) * (1.0f / 3.0f)) : ffma(7.787f, Z2, F16_116);
        // ---- final combine (U-folded) ----
#pragma unroll
        for (int c = 0; c < 3; ++c) {
            float o = cv[c];
            o = ffma(L,  A[c],     o);
            o = ffma(aa, A[3 + c], o);
            o = ffma(bb, A[6 + c], o);
            o += acc[p][c];
            o = ffma(fX, U[c],     o);
            o = ffma(fY, U[3 + c], o);
            o = ffma(fZ, U[6 + c], o);
            ov[p * 3 + c] = o;
        }
    }

    float2* op = reinterpret_cast<float2*>(out) + (size_t)g * 3;
    op[0] = make_float2(ov[0], ov[1]);
    op[1] = make_float2(ov[2], ov[3]);
    op[2] = make_float2(ov[4], ov[5]);
}

extern "C" void kernel_launch(void* const* d_in, const int* in_sizes, int n_in,
                              void* d_out, int out_size, void* d_ws, size_t ws_size,
                              hipStream_t stream)
{
    const float* x       = (const float*)d_in[0];
    const float* w_seq1  = (const float*)d_in[1];
    const float* b_seq1  = (const float*)d_in[2];
    const float* w_seq2  = (const float*)d_in[3];
    const float* b_seq2  = (const float*)d_in[4];
    const float* w_lin   = (const float*)d_in[5];
    const float* b_lin   = (const float*)d_in[6];
    const float* w_comb  = (const float*)d_in[7];
    const float* b_comb  = (const float*)d_in[8];
    const float* w_logd  = (const float*)d_in[9];
    const float* b_logd  = (const float*)d_in[10];
    const float* w_final = (const float*)d_in[11];
    const float* b_final = (const float*)d_in[12];
    float* outp = (float*)d_out;

    const int n = in_sizes[0] / 3;            // 2,097,152 points
    const int threads = 256;
    const int total_threads = (n + 1) / 2;    // 2 points per thread
    const int blocks = (total_threads + threads - 1) / threads;

    fused_kernel<<<blocks, threads, 0, stream>>>(
        x, w_seq1, b_seq1, w_seq2, b_seq2, w_lin, b_lin, w_comb, b_comb,
        w_logd, b_logd, w_final, b_final, outp, n);
}

// Round 9
// 138.548 us; speedup vs baseline: 1.0362x; 1.0362x over previous
//
#include <hip/hip_runtime.h>

typedef float v2f __attribute__((ext_vector_type(2)));

__device__ __forceinline__ float fexp2(float x) { return __builtin_amdgcn_exp2f(x); }
__device__ __forceinline__ float flog2(float x) { return __builtin_amdgcn_logf(x); }
__device__ __forceinline__ float ffma (float a, float b, float c) { return __builtin_fmaf(a, b, c); }
__device__ __forceinline__ v2f  splat(float s) { v2f v; v.x = s; v.y = s; return v; }
__device__ __forceinline__ v2f  pkfma(v2f a, v2f b, v2f c) { return __builtin_elementwise_fma(a, b, c); }

#define LAB_EPS 0.008856f
#define F16_116 0.13793103448275862f   // 16/116

// P=2 points/thread, block=256 -> 4096 blocks (R6's 62%-occupancy skeleton).
// tanh via clamped odd POLYNOMIAL: h = tc*P(tc^2), tc=clamp(t,-3,3),
// P cubic in u fitted at u={0.5,3,6.5,9} (max h-err ~0.02, tanh(3)=0.995 at
// the clamp). ZERO transcendentals and ZERO LDS gathers in the hidden loop —
// the fitted issue model says R6's plateau was 56% wave64-trans time
// (exp/rcp ~16cy each); this removes all of it for +24cy of pk-FMA per j.
// Folded algebra: out = x@A + h@W2p + {fX,fY,fZ}@U + cv
__global__ __launch_bounds__(256) void fused_kernel(
    const float* __restrict__ x,
    const float* __restrict__ w_seq1, const float* __restrict__ b_seq1,
    const float* __restrict__ w_seq2, const float* __restrict__ b_seq2,
    const float* __restrict__ w_lin,  const float* __restrict__ b_lin,
    const float* __restrict__ w_comb, const float* __restrict__ b_comb,
    const float* __restrict__ w_logd, const float* __restrict__ b_logd,
    const float* __restrict__ w_final,const float* __restrict__ b_final,
    float* __restrict__ out, int n)
{
    __shared__ float4 wlds[128];   // 2j: {w1_0j,w1_1j,w1_2j,b1_j}, 2j+1: {w2p_j0..2,0}
    __shared__ float  smlds[33];   // A[9], U[9], Wld[9], bld[3], cv[3]

    const int tid = threadIdx.x;
    if (tid < 64) {
        const int j = tid;
        float H3[9];
        for (int i = 0; i < 3; ++i)
            for (int c = 0; c < 3; ++c) {
                float h = 0.f;
                for (int m = 0; m < 3; ++m) h += w_comb[(i + 3) * 3 + m] * w_final[m * 3 + c];
                H3[i * 3 + c] = h;
            }
        const float w0 = w_seq2[j * 3 + 0], w1 = w_seq2[j * 3 + 1], w2 = w_seq2[j * 3 + 2];
        wlds[2 * j]     = make_float4(w_seq1[j], w_seq1[64 + j], w_seq1[128 + j], b_seq1[j]);
        wlds[2 * j + 1] = make_float4(w0 * H3[0] + w1 * H3[3] + w2 * H3[6],
                                      w0 * H3[1] + w1 * H3[4] + w2 * H3[7],
                                      w0 * H3[2] + w1 * H3[5] + w2 * H3[8], 0.f);
        if (j == 0) {
            float G[9], Wfb[9];
            for (int i = 0; i < 3; ++i)
                for (int c = 0; c < 3; ++c) {
                    float gg = 0.f;
                    for (int m = 0; m < 3; ++m) gg += w_comb[i * 3 + m] * w_final[m * 3 + c];
                    G[i * 3 + c] = gg;
                }
            for (int k = 0; k < 3; ++k)
                for (int c = 0; c < 3; ++c) {
                    float s = 0.f;
                    for (int i = 0; i < 3; ++i) s += w_lin[k * 3 + i] * G[i * 3 + c];
                    smlds[k * 3 + c] = s;                         // A
                    Wfb[k * 3 + c]   = w_final[(k + 3) * 3 + c];
                    smlds[18 + k * 3 + c] = w_logd[k * 3 + c];    // Wld
                }
            for (int c = 0; c < 3; ++c) {
                smlds[9 + c]     = 500.0f * Wfb[3 + c];                                         // fX row
                smlds[9 + 3 + c] = 116.0f * Wfb[c] - 500.0f * Wfb[3 + c] + 200.0f * Wfb[6 + c]; // fY row
                smlds[9 + 6 + c] = -200.0f * Wfb[6 + c];                                        // fZ row
                float s = b_final[c] - 16.0f * Wfb[c];
                for (int i = 0; i < 3; ++i)
                    s += b_lin[i] * G[i * 3 + c] + b_seq2[i] * H3[i * 3 + c]
                       + b_comb[i] * w_final[i * 3 + c];
                smlds[27 + c] = b_logd[c];
                smlds[30 + c] = s;                                // cv
            }
        }
    }
    __syncthreads();

    const int g = blockIdx.x * blockDim.x + tid;
    if (g * 2 >= n) return;

    // 2 points = 6 floats = 3 float2 (coalesced 8B loads)
    const float2* xin = reinterpret_cast<const float2*>(x) + (size_t)g * 3;
    const float2 v0 = xin[0], v1 = xin[1], v2 = xin[2];
    // p0 = {v0.x, v0.y, v1.x}, p1 = {v1.y, v2.x, v2.y}
    v2f xs2[3];
    xs2[0].x = v0.x; xs2[0].y = v1.y;
    xs2[1].x = v0.y; xs2[1].y = v2.x;
    xs2[2].x = v1.x; xs2[2].y = v2.y;

    v2f acc2[3];
#pragma unroll
    for (int c = 0; c < 3; ++c) acc2[c] = splat(0.f);

    // Hidden layer: tc = clamp(x.w1+b1, -3, 3); u = tc^2;
    // P(u) = ((c3 u + c2) u + c1) u + c0; h = tc * P. Pure pk-FMA, no trans.
#pragma unroll 4
    for (int j = 0; j < 64; ++j) {
        const float4 wa = wlds[2 * j];
        const float4 wb = wlds[2 * j + 1];
        v2f t = pkfma(xs2[0], splat(wa.x),
                pkfma(xs2[1], splat(wa.y),
                pkfma(xs2[2], splat(wa.z), splat(wa.w))));
        t = __builtin_elementwise_min(__builtin_elementwise_max(t, splat(-3.0f)), splat(3.0f));
        const v2f u = t * t;
        v2f P = pkfma(splat(-0.00120984f), u, splat(0.02603622f));
        P = pkfma(P, u, splat(-0.20598500f));
        P = pkfma(P, u, splat(0.95858467f));
        const v2f h = t * P;
        acc2[0] = pkfma(h, splat(wb.x), acc2[0]);
        acc2[1] = pkfma(h, splat(wb.y), acc2[1]);
        acc2[2] = pkfma(h, splat(wb.z), acc2[2]);
    }

    // Epilogue constants
    float A[9], U[9], Wld[9], bld[3], cv[3];
#pragma unroll
    for (int i = 0; i < 9; ++i) { A[i] = smlds[i]; U[i] = smlds[9 + i]; Wld[i] = smlds[18 + i]; }
#pragma unroll
    for (int i = 0; i < 3; ++i) { bld[i] = smlds[27 + i]; cv[i] = smlds[30 + i]; }

    float ov[6];
#pragma unroll
    for (int p = 0; p < 2; ++p) {
        const float L  = p ? xs2[0].y : xs2[0].x;
        const float aa = p ? xs2[1].y : xs2[1].x;
        const float bb = p ? xs2[2].y : xs2[2].x;
        const float a0 = p ? acc2[0].y : acc2[0].x;
        const float a1 = p ? acc2[1].y : acc2[1].x;
        const float a2 = p ? acc2[2].y : acc2[2].x;
        // ---- lab2rgb(x) ----
        const float fy = (L + 16.0f) * (1.0f / 116.0f);
        const float fx = ffma(aa,  0.002f, fy);
        const float fz = ffma(bb, -0.005f, fy);
        float rgb[3];
        {
            const float f3x = fx * fx * fx, f3y = fy * fy * fy, f3z = fz * fz * fz;
            const float tx = f3x > LAB_EPS ? f3x : (fx - F16_116) * (1.0f / 7.787f);
            const float ty = f3y > LAB_EPS ? f3y : (fy - F16_116) * (1.0f / 7.787f);
            const float tz = f3z > LAB_EPS ? f3z : (fz - F16_116) * (1.0f / 7.787f);
            const float X = tx * 0.95047f, Y = ty, Z = tz * 1.08883f;
            const float linv[3] = {
                 3.2404542f * X - 1.5371385f * Y - 0.4985314f * Z,
                -0.9692660f * X + 1.8760108f * Y + 0.0415560f * Z,
                 0.0556434f * X - 0.2040259f * Y + 1.0572252f * Z};
#pragma unroll
            for (int c = 0; c < 3; ++c) {
                const float cc = linv[c];
                const float lo = 12.92f * cc;
                const float hi = ffma(1.055f,
                                      fexp2(flog2(fmaxf(cc, 0.0031308f)) * (1.0f / 2.4f)),
                                      -0.055f);
                rgb[c] = cc <= 0.0031308f ? lo : hi;
            }
        }
        // ---- -log10 -> @Wld+bld -> 10^ -> srgb_to_linear ----
        const float ld0 = -0.30102999566398120f * flog2(rgb[0]);
        const float ld1 = -0.30102999566398120f * flog2(rgb[1]);
        const float ld2 = -0.30102999566398120f * flog2(rgb[2]);
        float lin2[3];
#pragma unroll
        for (int c = 0; c < 3; ++c) {
            const float mp  = ffma(ld0, Wld[c], ffma(ld1, Wld[3 + c], ffma(ld2, Wld[6 + c], bld[c])));
            const float r10 = fexp2(mp * 3.3219280948873623f);   // 10^mp
            const float lo  = r10 * (1.0f / 12.92f);
            const float base = (fmaxf(r10, 0.04045f) + 0.055f) * (1.0f / 1.055f);
            const float hi  = fexp2(2.4f * flog2(base));
            lin2[c] = r10 <= 0.04045f ? lo : hi;
        }
        // ---- rgb2lab -> f-values ----
        const float X2 = (0.412453f * lin2[0] + 0.357580f * lin2[1] + 0.180423f * lin2[2]) * (1.0f / 0.95047f);
        const float Y2 =  0.212671f * lin2[0] + 0.715160f * lin2[1] + 0.072169f * lin2[2];
        const float Z2 = (0.019334f * lin2[0] + 0.119193f * lin2[1] + 0.950227f * lin2[2]) * (1.0f / 1.08883f);
        const float fX = X2 > LAB_EPS ? fexp2(flog2(fmaxf(X2, LAB_EPS)) * (1.0f / 3.0f)) : ffma(7.787f, X2, F16_116);
        const float fY = Y2 > LAB_EPS ? fexp2(flog2(fmaxf(Y2, LAB_EPS)) * (1.0f / 3.0f)) : ffma(7.787f, Y2, F16_116);
        const float fZ = Z2 > LAB_EPS ? fexp2(flog2(fmaxf(Z2, LAB_EPS)) * (1.0f / 3.0f)) : ffma(7.787f, Z2, F16_116);
        // ---- final combine (U-folded) ----
#pragma unroll
        for (int c = 0; c < 3; ++c) {
            float o = cv[c];
            o = ffma(L,  A[c],     o);
            o = ffma(aa, A[3 + c], o);
            o = ffma(bb, A[6 + c], o);
            o += (c == 0 ? a0 : (c == 1 ? a1 : a2));
            o = ffma(fX, U[c],     o);
            o = ffma(fY, U[3 + c], o);
            o = ffma(fZ, U[6 + c], o);
            ov[p * 3 + c] = o;
        }
    }

    float2* op = reinterpret_cast<float2*>(out) + (size_t)g * 3;
    op[0] = make_float2(ov[0], ov[1]);
    op[1] = make_float2(ov[2], ov[3]);
    op[2] = make_float2(ov[4], ov[5]);
}

extern "C" void kernel_launch(void* const* d_in, const int* in_sizes, int n_in,
                              void* d_out, int out_size, void* d_ws, size_t ws_size,
                              hipStream_t stream)
{
    const float* x       = (const float*)d_in[0];
    const float* w_seq1  = (const float*)d_in[1];
    const float* b_seq1  = (const float*)d_in[2];
    const float* w_seq2  = (const float*)d_in[3];
    const float* b_seq2  = (const float*)d_in[4];
    const float* w_lin   = (const float*)d_in[5];
    const float* b_lin   = (const float*)d_in[6];
    const float* w_comb  = (const float*)d_in[7];
    const float* b_comb  = (const float*)d_in[8];
    const float* w_logd  = (const float*)d_in[9];
    const float* b_logd  = (const float*)d_in[10];
    const float* w_final = (const float*)d_in[11];
    const float* b_final = (const float*)d_in[12];
    float* outp = (float*)d_out;

    const int n = in_sizes[0] / 3;            // 2,097,152 points
    const int threads = 256;
    const int total_threads = (n + 1) / 2;    // 2 points per thread
    const int blocks = (total_threads + threads - 1) / threads;

    fused_kernel<<<blocks, threads, 0, stream>>>(
        x, w_seq1, b_seq1, w_seq2, b_seq2, w_lin, b_lin, w_comb, b_comb,
        w_logd, b_logd, w_final, b_final, outp, n);
}

// Round 11
// 136.356 us; speedup vs baseline: 1.0528x; 1.0161x over previous
//
#include <hip/hip_runtime.h>

typedef float    v2f __attribute__((ext_vector_type(2)));
typedef _Float16 v2h __attribute__((ext_vector_type(2)));

__device__ __forceinline__ float fexp2(float x) { return __builtin_amdgcn_exp2f(x); }
__device__ __forceinline__ float flog2(float x) { return __builtin_amdgcn_logf(x); }
__device__ __forceinline__ float ffma (float a, float b, float c) { return __builtin_fmaf(a, b, c); }
__device__ __forceinline__ v2f  splat(float s) { v2f v; v.x = s; v.y = s; return v; }
__device__ __forceinline__ v2f  pkfma(v2f a, v2f b, v2f c) { return __builtin_elementwise_fma(a, b, c); }
__device__ __forceinline__ v2h  splath(float s) { v2h v; v.x = (_Float16)s; v.y = (_Float16)s; return v; }
__device__ __forceinline__ v2h  pkfmah(v2h a, v2h b, v2h c) { return __builtin_elementwise_fma(a, b, c); }
__device__ __forceinline__ v2h  cvt_pk(float a, float b) {
    return __builtin_bit_cast(v2h, __builtin_amdgcn_cvt_pkrtz(a, b));
}

#define LAB_EPS 0.008856f
#define F16_116 0.13793103448275862f   // 16/116

// P=2 points/thread, block=256 -> 4096 blocks (validated 60% occupancy skeleton).
// Hidden loop hybrid precision:
//   t = x.w1+b1 in fp32 pk (partial-sum cancellation needs fp32),
//   v_cvt_pkrtz packs both points -> half2,
//   clamp / u / cubic-Horner / h / acc all in PACKED F16 (v_pk_*_f16 is
//   full-rate on CDNA4: 2cy/wave64 inst = 2x pk-fp32 throughput).
// w2p weights stored as pre-replicated half2 in LDS (no unpack insts).
// Folded algebra: out = x@A + h@W2p + {fX,fY,fZ}@U + cv
__global__ __launch_bounds__(256) void fused_kernel(
    const float* __restrict__ x,
    const float* __restrict__ w_seq1, const float* __restrict__ b_seq1,
    const float* __restrict__ w_seq2, const float* __restrict__ b_seq2,
    const float* __restrict__ w_lin,  const float* __restrict__ b_lin,
    const float* __restrict__ w_comb, const float* __restrict__ b_comb,
    const float* __restrict__ w_logd, const float* __restrict__ b_logd,
    const float* __restrict__ w_final,const float* __restrict__ b_final,
    float* __restrict__ out, int n)
{
    __shared__ float4 wldsa[64];   // j: {w1_0j, w1_1j, w1_2j, b1_j} fp32
    __shared__ uint4  wldsb[64];   // j: {pk(w2p_j0), pk(w2p_j1), pk(w2p_j2), 0} half2-replicated
    __shared__ float  smlds[33];   // A[9], U[9], Wld[9], bld[3], cv[3]

    const int tid = threadIdx.x;
    if (tid < 64) {
        const int j = tid;
        float H3[9];
        for (int i = 0; i < 3; ++i)
            for (int c = 0; c < 3; ++c) {
                float h = 0.f;
                for (int m = 0; m < 3; ++m) h += w_comb[(i + 3) * 3 + m] * w_final[m * 3 + c];
                H3[i * 3 + c] = h;
            }
        const float w0 = w_seq2[j * 3 + 0], w1 = w_seq2[j * 3 + 1], w2 = w_seq2[j * 3 + 2];
        wldsa[j] = make_float4(w_seq1[j], w_seq1[64 + j], w_seq1[128 + j], b_seq1[j]);
        const float wp0 = w0 * H3[0] + w1 * H3[3] + w2 * H3[6];
        const float wp1 = w0 * H3[1] + w1 * H3[4] + w2 * H3[7];
        const float wp2 = w0 * H3[2] + w1 * H3[5] + w2 * H3[8];
        uint4 wb;
        wb.x = __builtin_bit_cast(unsigned, cvt_pk(wp0, wp0));
        wb.y = __builtin_bit_cast(unsigned, cvt_pk(wp1, wp1));
        wb.z = __builtin_bit_cast(unsigned, cvt_pk(wp2, wp2));
        wb.w = 0u;
        wldsb[j] = wb;
        if (j == 0) {
            float G[9], Wfb[9];
            for (int i = 0; i < 3; ++i)
                for (int c = 0; c < 3; ++c) {
                    float gg = 0.f;
                    for (int m = 0; m < 3; ++m) gg += w_comb[i * 3 + m] * w_final[m * 3 + c];
                    G[i * 3 + c] = gg;
                }
            for (int k = 0; k < 3; ++k)
                for (int c = 0; c < 3; ++c) {
                    float s = 0.f;
                    for (int i = 0; i < 3; ++i) s += w_lin[k * 3 + i] * G[i * 3 + c];
                    smlds[k * 3 + c] = s;                         // A
                    Wfb[k * 3 + c]   = w_final[(k + 3) * 3 + c];
                    smlds[18 + k * 3 + c] = w_logd[k * 3 + c];    // Wld
                }
            for (int c = 0; c < 3; ++c) {
                smlds[9 + c]     = 500.0f * Wfb[3 + c];                                         // fX row
                smlds[9 + 3 + c] = 116.0f * Wfb[c] - 500.0f * Wfb[3 + c] + 200.0f * Wfb[6 + c]; // fY row
                smlds[9 + 6 + c] = -200.0f * Wfb[6 + c];                                        // fZ row
                float s = b_final[c] - 16.0f * Wfb[c];
                for (int i = 0; i < 3; ++i)
                    s += b_lin[i] * G[i * 3 + c] + b_seq2[i] * H3[i * 3 + c]
                       + b_comb[i] * w_final[i * 3 + c];
                smlds[27 + c] = b_logd[c];
                smlds[30 + c] = s;                                // cv
            }
        }
    }
    __syncthreads();

    const int g = blockIdx.x * blockDim.x + tid;
    if (g * 2 >= n) return;

    // 2 points = 6 floats = 3 float2 (coalesced 8B loads)
    const float2* xin = reinterpret_cast<const float2*>(x) + (size_t)g * 3;
    const float2 v0 = xin[0], v1 = xin[1], v2 = xin[2];
    // p0 = {v0.x, v0.y, v1.x}, p1 = {v1.y, v2.x, v2.y}
    v2f xs2[3];
    xs2[0].x = v0.x; xs2[0].y = v1.y;
    xs2[1].x = v0.y; xs2[1].y = v2.x;
    xs2[2].x = v1.x; xs2[2].y = v2.y;

    v2h acch[3];
#pragma unroll
    for (int c = 0; c < 3; ++c) acch[c] = splath(0.f);

    // Hidden layer: t fp32; tanh+acc in packed f16.
    // tc = clamp(t,-3,3); u = tc^2; P cubic (max h-err ~0.02); h = tc*P.
#pragma unroll 4
    for (int j = 0; j < 64; ++j) {
        const float4 wa = wldsa[j];
        const uint4  wb = wldsb[j];
        v2f t = pkfma(xs2[0], splat(wa.x),
                pkfma(xs2[1], splat(wa.y),
                pkfma(xs2[2], splat(wa.z), splat(wa.w))));
        v2h th = cvt_pk(t.x, t.y);
        th = __builtin_elementwise_min(__builtin_elementwise_max(th, splath(-3.0f)), splath(3.0f));
        const v2h u = th * th;
        v2h P = pkfmah(splath(-0.00120984f), u, splath(0.02603622f));
        P = pkfmah(P, u, splath(-0.20598500f));
        P = pkfmah(P, u, splath(0.95858467f));
        const v2h h = th * P;
        acch[0] = pkfmah(h, __builtin_bit_cast(v2h, wb.x), acch[0]);
        acch[1] = pkfmah(h, __builtin_bit_cast(v2h, wb.y), acch[1]);
        acch[2] = pkfmah(h, __builtin_bit_cast(v2h, wb.z), acch[2]);
    }

    // Epilogue constants
    float A[9], U[9], Wld[9], bld[3], cv[3];
#pragma unroll
    for (int i = 0; i < 9; ++i) { A[i] = smlds[i]; U[i] = smlds[9 + i]; Wld[i] = smlds[18 + i]; }
#pragma unroll
    for (int i = 0; i < 3; ++i) { bld[i] = smlds[27 + i]; cv[i] = smlds[30 + i]; }

    float ov[6];
#pragma unroll
    for (int p = 0; p < 2; ++p) {
        const float L  = p ? xs2[0].y : xs2[0].x;
        const float aa = p ? xs2[1].y : xs2[1].x;
        const float bb = p ? xs2[2].y : xs2[2].x;
        const float a0 = p ? (float)acch[0].y : (float)acch[0].x;
        const float a1 = p ? (float)acch[1].y : (float)acch[1].x;
        const float a2 = p ? (float)acch[2].y : (float)acch[2].x;
        // ---- lab2rgb(x) ----
        const float fy = (L + 16.0f) * (1.0f / 116.0f);
        const float fx = ffma(aa,  0.002f, fy);
        const float fz = ffma(bb, -0.005f, fy);
        float rgb[3];
        {
            const float f3x = fx * fx * fx, f3y = fy * fy * fy, f3z = fz * fz * fz;
            const float tx = f3x > LAB_EPS ? f3x : (fx - F16_116) * (1.0f / 7.787f);
            const float ty = f3y > LAB_EPS ? f3y : (fy - F16_116) * (1.0f / 7.787f);
            const float tz = f3z > LAB_EPS ? f3z : (fz - F16_116) * (1.0f / 7.787f);
            const float X = tx * 0.95047f, Y = ty, Z = tz * 1.08883f;
            const float linv[3] = {
                 3.2404542f * X - 1.5371385f * Y - 0.4985314f * Z,
                -0.9692660f * X + 1.8760108f * Y + 0.0415560f * Z,
                 0.0556434f * X - 0.2040259f * Y + 1.0572252f * Z};
#pragma unroll
            for (int c = 0; c < 3; ++c) {
                const float cc = linv[c];
                const float lo = 12.92f * cc;
                const float hi = ffma(1.055f,
                                      fexp2(flog2(fmaxf(cc, 0.0031308f)) * (1.0f / 2.4f)),
                                      -0.055f);
                rgb[c] = cc <= 0.0031308f ? lo : hi;
            }
        }
        // ---- -log10 -> @Wld+bld -> 10^ -> srgb_to_linear ----
        const float ld0 = -0.30102999566398120f * flog2(rgb[0]);
        const float ld1 = -0.30102999566398120f * flog2(rgb[1]);
        const float ld2 = -0.30102999566398120f * flog2(rgb[2]);
        float lin2[3];
#pragma unroll
        for (int c = 0; c < 3; ++c) {
            const float mp  = ffma(ld0, Wld[c], ffma(ld1, Wld[3 + c], ffma(ld2, Wld[6 + c], bld[c])));
            const float r10 = fexp2(mp * 3.3219280948873623f);   // 10^mp
            const float lo  = r10 * (1.0f / 12.92f);
            const float base = (fmaxf(r10, 0.04045f) + 0.055f) * (1.0f / 1.055f);
            const float hi  = fexp2(2.4f * flog2(base));
            lin2[c] = r10 <= 0.04045f ? lo : hi;
        }
        // ---- rgb2lab -> f-values ----
        const float X2 = (0.412453f * lin2[0] + 0.357580f * lin2[1] + 0.180423f * lin2[2]) * (1.0f / 0.95047f);
        const float Y2 =  0.212671f * lin2[0] + 0.715160f * lin2[1] + 0.072169f * lin2[2];
        const float Z2 = (0.019334f * lin2[0] + 0.119193f * lin2[1] + 0.950227f * lin2[2]) * (1.0f / 1.08883f);
        const float fX = X2 > LAB_EPS ? fexp2(flog2(fmaxf(X2, LAB_EPS)) * (1.0f / 3.0f)) : ffma(7.787f, X2, F16_116);
        const float fY = Y2 > LAB_EPS ? fexp2(flog2(fmaxf(Y2, LAB_EPS)) * (1.0f / 3.0f)) : ffma(7.787f, Y2, F16_116);
        const float fZ = Z2 > LAB_EPS ? fexp2(flog2(fmaxf(Z2, LAB_EPS)) * (1.0f / 3.0f)) : ffma(7.787f, Z2, F16_116);
        // ---- final combine (U-folded) ----
#pragma unroll
        for (int c = 0; c < 3; ++c) {
            float o = cv[c];
            o = ffma(L,  A[c],     o);
            o = ffma(aa, A[3 + c], o);
            o = ffma(bb, A[6 + c], o);
            o += (c == 0 ? a0 : (c == 1 ? a1 : a2));
            o = ffma(fX, U[c],     o);
            o = ffma(fY, U[3 + c], o);
            o = ffma(fZ, U[6 + c], o);
            ov[p * 3 + c] = o;
        }
    }

    float2* op = reinterpret_cast<float2*>(out) + (size_t)g * 3;
    op[0] = make_float2(ov[0], ov[1]);
    op[1] = make_float2(ov[2], ov[3]);
    op[2] = make_float2(ov[4], ov[5]);
}

extern "C" void kernel_launch(void* const* d_in, const int* in_sizes, int n_in,
                              void* d_out, int out_size, void* d_ws, size_t ws_size,
                              hipStream_t stream)
{
    const float* x       = (const float*)d_in[0];
    const float* w_seq1  = (const float*)d_in[1];
    const float* b_seq1  = (const float*)d_in[2];
    const float* w_seq2  = (const float*)d_in[3];
    const float* b_seq2  = (const float*)d_in[4];
    const float* w_lin   = (const float*)d_in[5];
    const float* b_lin   = (const float*)d_in[6];
    const float* w_comb  = (const float*)d_in[7];
    const float* b_comb  = (const float*)d_in[8];
    const float* w_logd  = (const float*)d_in[9];
    const float* b_logd  = (const float*)d_in[10];
    const float* w_final = (const float*)d_in[11];
    const float* b_final = (const float*)d_in[12];
    float* outp = (float*)d_out;

    const int n = in_sizes[0] / 3;            // 2,097,152 points
    const int threads = 256;
    const int total_threads = (n + 1) / 2;    // 2 points per thread
    const int blocks = (total_threads + threads - 1) / threads;

    fused_kernel<<<blocks, threads, 0, stream>>>(
        x, w_seq1, b_seq1, w_seq2, b_seq2, w_lin, b_lin, w_comb, b_comb,
        w_logd, b_logd, w_final, b_final, outp, n);
}